// Round 1
// baseline (2427.189 us; speedup 1.0000x reference)
//
#include <hip/hip_runtime.h>

#define B_   32
#define C_   256
#define N_   1024
#define L_   12
#define H_   8
#define DK_  32
#define NL_  (N_*L_)            // 12288
#define CNL_ (C_*NL_)           // 3145728
#define ND_  (N_*DK_)           // 32768
#define HLN_ (H_*L_*N_)         // 98304
#define SCALE_ 0.17677669529663687f

// ---------------- K0: softmax over DK of s_bank * scale -> ks ----------------
__global__ __launch_bounds__(256) void k_key_softmax(const float* __restrict__ sb,
                                                     float* __restrict__ ks) {
    int row = blockIdx.x * 256 + threadIdx.x;     // over H*L*N rows
    if (row >= HLN_) return;
    const float4* src = (const float4*)(sb + (size_t)row * DK_);
    float v[DK_];
#pragma unroll
    for (int i = 0; i < 8; i++) {
        float4 t4 = src[i];
        v[4*i+0] = t4.x; v[4*i+1] = t4.y; v[4*i+2] = t4.z; v[4*i+3] = t4.w;
    }
    float m = v[0];
#pragma unroll
    for (int i = 1; i < DK_; i++) m = fmaxf(m, v[i]);
    float s = 0.f;
#pragma unroll
    for (int i = 0; i < DK_; i++) { v[i] = __expf((v[i] - m) * SCALE_); s += v[i]; }
    float inv = 1.f / s;
    float4* dst = (float4*)(ks + (size_t)row * DK_);
#pragma unroll
    for (int i = 0; i < 8; i++) {
        float4 t4;
        t4.x = v[4*i+0]*inv; t4.y = v[4*i+1]*inv; t4.z = v[4*i+2]*inv; t4.w = v[4*i+3]*inv;
        dst[i] = t4;
    }
}

// ---------------- K1: fused q,v 1x1 conv + relu, write [B,H,L,N,DK] ----------
// tile: 64 out-ch x 192 spatial (16 n x 12 l), BK=16, 256 threads, 4x12 micro x2
__global__ __launch_bounds__(256) void k_conv_qv(const float* __restrict__ x,
                                                 const float* __restrict__ wq,
                                                 const float* __restrict__ bq,
                                                 const float* __restrict__ wv,
                                                 const float* __restrict__ bv,
                                                 float* __restrict__ qr,
                                                 float* __restrict__ vv) {
    __shared__ float Xs[16 * 196];
    __shared__ float Wqs[16 * 68];
    __shared__ float Wvs[16 * 68];
    const int nt = blockIdx.x;      // 0..63   (16 n each)
    const int ob = blockIdx.y;      // 0..3    (64 o each)
    const int b  = blockIdx.z;      // 0..31
    const int t  = threadIdx.x;
    const int tn = t & 15;          // col group (one n, 12 l)
    const int tm = t >> 4;          // row group (4 o)
    const int o0 = ob * 64;
    const int s0 = nt * 192;        // spatial offset (n0*12)
    const float* xb = x + (size_t)b * CNL_ + s0;

    float accq[4][12] = {};
    float accv[4][12] = {};

    for (int kb = 0; kb < C_ / 16; kb++) {
        const int k0 = kb * 16;
        // X tile: 16 ch x 192 cols = 768 float4
#pragma unroll
        for (int i = 0; i < 3; i++) {
            int e4 = t + i * 256;
            int ci = e4 / 48, j4 = e4 % 48;
            float4 val = *(const float4*)(xb + (size_t)(k0 + ci) * NL_ + j4 * 4);
            *(float4*)&Xs[ci * 196 + j4 * 4] = val;
        }
        // W tiles (transposed into LDS): 64 o x 16 k each
        {
            int oo = t >> 2, ci0 = (t & 3) * 4;
            float4 a = *(const float4*)(wq + (size_t)(o0 + oo) * C_ + k0 + ci0);
            Wqs[(ci0+0)*68 + oo] = a.x; Wqs[(ci0+1)*68 + oo] = a.y;
            Wqs[(ci0+2)*68 + oo] = a.z; Wqs[(ci0+3)*68 + oo] = a.w;
            float4 c = *(const float4*)(wv + (size_t)(o0 + oo) * C_ + k0 + ci0);
            Wvs[(ci0+0)*68 + oo] = c.x; Wvs[(ci0+1)*68 + oo] = c.y;
            Wvs[(ci0+2)*68 + oo] = c.z; Wvs[(ci0+3)*68 + oo] = c.w;
        }
        __syncthreads();
#pragma unroll
        for (int k = 0; k < 16; k++) {
            float4 aq4 = *(float4*)&Wqs[k * 68 + tm * 4];
            float4 av4 = *(float4*)&Wvs[k * 68 + tm * 4];
            float aq[4] = {aq4.x, aq4.y, aq4.z, aq4.w};
            float av[4] = {av4.x, av4.y, av4.z, av4.w};
            float4 x0 = *(float4*)&Xs[k * 196 + tn * 12 + 0];
            float4 x1 = *(float4*)&Xs[k * 196 + tn * 12 + 4];
            float4 x2 = *(float4*)&Xs[k * 196 + tn * 12 + 8];
            float xr[12] = {x0.x,x0.y,x0.z,x0.w, x1.x,x1.y,x1.z,x1.w, x2.x,x2.y,x2.z,x2.w};
#pragma unroll
            for (int r = 0; r < 4; r++)
#pragma unroll
                for (int j = 0; j < 12; j++) {
                    accq[r][j] += aq[r] * xr[j];
                    accv[r][j] += av[r] * xr[j];
                }
        }
        __syncthreads();
    }
    // direct scattered write into [B,H,L,N,DK]; L2 assembles lines
    const int n = nt * 16 + tn;
#pragma unroll
    for (int r = 0; r < 4; r++) {
        int o = o0 + tm * 4 + r;
        int h = o >> 5, y = o & 31;
        float bqv = bq[o], bvv = bv[o];
#pragma unroll
        for (int l = 0; l < 12; l++) {
            size_t idx = ((size_t)(b * H_ + h) * L_ + l) * ND_ + (size_t)n * DK_ + y;
            qr[idx] = fmaxf(accq[r][l] + bqv, 0.f);
            vv[idx] = fmaxf(accv[r][l] + bvv, 0.f);
        }
    }
}

// ---------------- K2: per (b,h,l): kv = ks^T vv; qkv = softmax(qr)*kv --------
// qkv written in place over qr
__global__ __launch_bounds__(256) void k_attn(const float* __restrict__ ks,
                                              float* __restrict__ qr,
                                              const float* __restrict__ vv) {
    __shared__ float kv[DK_ * DK_];     // 32x32
    __shared__ float un[8448];          // union: ks_t|vv_t (4096) / kvp (4096) / qtile 256x33
    const int bid = blockIdx.x;         // b*96 + h*12 + l
    const int b = bid / 96;
    const int hl = bid % 96;
    const float* ksb = ks + (size_t)hl * ND_;
    float* qb = qr + ((size_t)b * 96 + hl) * ND_;
    const float* vb = vv + ((size_t)b * 96 + hl) * ND_;
    const int t = threadIdx.x;
    const int p = t >> 6;               // wave id = n-partition
    const int lane = t & 63;
    const int x0 = (lane & 7) * 4, y0 = (lane >> 3) * 4;

    float* ks_t = un;
    float* vv_t = un + 2048;
    float acc[4][4] = {};

    for (int tile = 0; tile < 16; tile++) {
        const int nb = tile * 64;
#pragma unroll
        for (int i = 0; i < 2; i++) {
            int e4 = t + i * 256;
            *(float4*)&ks_t[e4 * 4] = *(const float4*)(ksb + (size_t)nb * DK_ + e4 * 4);
            *(float4*)&vv_t[e4 * 4] = *(const float4*)(vb + (size_t)nb * DK_ + e4 * 4);
        }
        __syncthreads();
#pragma unroll
        for (int nn = 0; nn < 16; nn++) {
            int nloc = p * 16 + nn;
            float4 kk4 = *(float4*)&ks_t[nloc * 32 + x0];
            float4 vv4 = *(float4*)&vv_t[nloc * 32 + y0];
            float ax[4] = {kk4.x, kk4.y, kk4.z, kk4.w};
            float by[4] = {vv4.x, vv4.y, vv4.z, vv4.w};
#pragma unroll
            for (int xi = 0; xi < 4; xi++)
#pragma unroll
                for (int yi = 0; yi < 4; yi++) acc[xi][yi] += ax[xi] * by[yi];
        }
        __syncthreads();
    }
    // reduce the 4 n-partitions
    float* kvp = un;
#pragma unroll
    for (int xi = 0; xi < 4; xi++)
#pragma unroll
        for (int yi = 0; yi < 4; yi++)
            kvp[p * 1024 + (x0 + xi) * 32 + (y0 + yi)] = acc[xi][yi];
    __syncthreads();
#pragma unroll
    for (int i = 0; i < 4; i++) {
        int idx = t + i * 256;
        kv[idx] = kvp[idx] + kvp[1024 + idx] + kvp[2048 + idx] + kvp[3072 + idx];
    }
    __syncthreads();

    // phase 2: 4 tiles of 256 n-rows; thread t owns row t of the tile
    float* qt = un;   // 256 x 33 (padded)
    for (int tile = 0; tile < 4; tile++) {
        const int n1 = tile * 256;
#pragma unroll
        for (int i = 0; i < 8; i++) {
            int e4 = t + i * 256;
            int r = e4 >> 3, c0 = (e4 & 7) * 4;
            float4 val = *(const float4*)(qb + (size_t)(n1 + r) * DK_ + c0);
            qt[r * 33 + c0 + 0] = val.x; qt[r * 33 + c0 + 1] = val.y;
            qt[r * 33 + c0 + 2] = val.z; qt[r * 33 + c0 + 3] = val.w;
        }
        __syncthreads();
        {
            float q[DK_];
#pragma unroll
            for (int j = 0; j < DK_; j++) q[j] = qt[t * 33 + j];
            float m = q[0];
#pragma unroll
            for (int j = 1; j < DK_; j++) m = fmaxf(m, q[j]);
            float s = 0.f;
#pragma unroll
            for (int j = 0; j < DK_; j++) { q[j] = __expf((q[j] - m) * SCALE_); s += q[j]; }
            float inv = 1.f / s;
            float o[DK_] = {};
#pragma unroll
            for (int x = 0; x < DK_; x++) {
                float px = q[x];
#pragma unroll
                for (int y4 = 0; y4 < 8; y4++) {
                    float4 kk = *(float4*)&kv[x * 32 + y4 * 4];
                    o[y4*4+0] += px * kk.x; o[y4*4+1] += px * kk.y;
                    o[y4*4+2] += px * kk.z; o[y4*4+3] += px * kk.w;
                }
            }
            __syncthreads();   // everyone done reading q rows before overwrite
#pragma unroll
            for (int j = 0; j < DK_; j++) qt[t * 33 + j] = o[j] * inv;
        }
        __syncthreads();
#pragma unroll
        for (int i = 0; i < 8; i++) {
            int e4 = t + i * 256;
            int r = e4 >> 3, c0 = (e4 & 7) * 4;
            float4 val;
            val.x = qt[r * 33 + c0 + 0]; val.y = qt[r * 33 + c0 + 1];
            val.z = qt[r * 33 + c0 + 2]; val.w = qt[r * 33 + c0 + 3];
            *(float4*)(qb + (size_t)(n1 + r) * DK_ + c0) = val;
        }
        __syncthreads();
    }
}

// ---------------- K3: final conv from [B,H,L,N,DK] -> relu -> [B,C,N,L] ------
__global__ __launch_bounds__(256) void k_conv_out(const float* __restrict__ qkv,
                                                  const float* __restrict__ cw,
                                                  const float* __restrict__ cb,
                                                  float* __restrict__ out) {
    __shared__ float Xs[DK_ * 196];
    __shared__ float Ws[DK_ * 68];
    const int nt = blockIdx.x;      // 0..63
    const int ob = blockIdx.y;      // 0..3
    const int b  = blockIdx.z;
    const int t  = threadIdx.x;
    const int tn = t & 15, tm = t >> 4;
    const int o0 = ob * 64;
    const int n0 = nt * 16;

    float acc[4][12] = {};
    for (int h = 0; h < H_; h++) {
        // X tile: transpose [n,x] -> Xs[x][n_local*12 + l]
#pragma unroll
        for (int l = 0; l < 12; l++) {
            const float* src = qkv + ((size_t)(b * H_ + h) * L_ + l) * ND_ + (size_t)n0 * DK_;
            int e = 2 * t;
            int ni = e >> 5, xx = e & 31;
            float2 val = *(const float2*)(src + e);
            Xs[(xx + 0) * 196 + ni * 12 + l] = val.x;
            Xs[(xx + 1) * 196 + ni * 12 + l] = val.y;
        }
        // W tile: cw[o0+oo][h*32+x] -> Ws[x][oo]
#pragma unroll
        for (int i = 0; i < 2; i++) {
            int e4 = t + i * 256;
            int oo = e4 >> 3, xx0 = (e4 & 7) * 4;
            float4 a = *(const float4*)(cw + (size_t)(o0 + oo) * C_ + h * DK_ + xx0);
            Ws[(xx0+0)*68 + oo] = a.x; Ws[(xx0+1)*68 + oo] = a.y;
            Ws[(xx0+2)*68 + oo] = a.z; Ws[(xx0+3)*68 + oo] = a.w;
        }
        __syncthreads();
#pragma unroll
        for (int k = 0; k < DK_; k++) {
            float4 a4 = *(float4*)&Ws[k * 68 + tm * 4];
            float a[4] = {a4.x, a4.y, a4.z, a4.w};
            float4 x0 = *(float4*)&Xs[k * 196 + tn * 12 + 0];
            float4 x1 = *(float4*)&Xs[k * 196 + tn * 12 + 4];
            float4 x2 = *(float4*)&Xs[k * 196 + tn * 12 + 8];
            float xr[12] = {x0.x,x0.y,x0.z,x0.w, x1.x,x1.y,x1.z,x1.w, x2.x,x2.y,x2.z,x2.w};
#pragma unroll
            for (int r = 0; r < 4; r++)
#pragma unroll
                for (int j = 0; j < 12; j++) acc[r][j] += a[r] * xr[j];
        }
        __syncthreads();
    }
    const int n = n0 + tn;
#pragma unroll
    for (int r = 0; r < 4; r++) {
        int o = o0 + tm * 4 + r;
        float bb = cb[o];
        float res[12];
#pragma unroll
        for (int l = 0; l < 12; l++) res[l] = fmaxf(acc[r][l] + bb, 0.f);
        float* dst = out + ((size_t)(b * C_ + o) * N_ + n) * L_;
        *(float4*)(dst + 0) = make_float4(res[0], res[1], res[2], res[3]);
        *(float4*)(dst + 4) = make_float4(res[4], res[5], res[6], res[7]);
        *(float4*)(dst + 8) = make_float4(res[8], res[9], res[10], res[11]);
    }
}

extern "C" void kernel_launch(void* const* d_in, const int* in_sizes, int n_in,
                              void* d_out, int out_size, void* d_ws, size_t ws_size,
                              hipStream_t stream) {
    const float* input = (const float*)d_in[0];
    const float* q_w   = (const float*)d_in[1];
    const float* q_b   = (const float*)d_in[2];
    const float* v_w   = (const float*)d_in[3];
    const float* v_b   = (const float*)d_in[4];
    const float* c_w   = (const float*)d_in[5];
    const float* c_b   = (const float*)d_in[6];
    const float* s_bank= (const float*)d_in[7];
    float* out = (float*)d_out;

    float* ws = (float*)d_ws;
    float* ks = ws;                                   // H*L*N*DK      = 3,145,728
    float* qr = ws + (size_t)HLN_ * DK_;              // B*H*L*N*DK    = 100,663,296
    float* vv = qr + (size_t)B_ * HLN_ * DK_;         // B*H*L*N*DK

    k_key_softmax<<<dim3((HLN_ + 255) / 256), dim3(256), 0, stream>>>(s_bank, ks);
    k_conv_qv<<<dim3(64, 4, 32), dim3(256), 0, stream>>>(input, q_w, q_b, v_w, v_b, qr, vv);
    k_attn<<<dim3(B_ * H_ * L_), dim3(256), 0, stream>>>(ks, qr, vv);
    k_conv_out<<<dim3(64, 4, 32), dim3(256), 0, stream>>>(qr, c_w, c_b, out);
}

// Round 2
// 1222.384 us; speedup vs baseline: 1.9856x; 1.9856x over previous
//
#include <hip/hip_runtime.h>

#define B_   32
#define C_   256
#define N_   1024
#define L_   12
#define H_   8
#define DK_  32
#define NL_  12288
#define CNL_ 3145728
#define ND_  32768
#define HLN_ 98304
#define SCALE_ 0.17677669529663687f

typedef _Float16 half8 __attribute__((ext_vector_type(8)));
typedef _Float16 half4 __attribute__((ext_vector_type(4)));
typedef float f32x4 __attribute__((ext_vector_type(4)));

__device__ __forceinline__ int div12(int s) { return (int)(((unsigned)s * 43691u) >> 19); }

// ---------------- K0: softmax over DK of s_bank * scale -> ks (fp32) --------
__global__ __launch_bounds__(256) void k_key_softmax(const float* __restrict__ sb,
                                                     float* __restrict__ ks) {
    int row = blockIdx.x * 256 + threadIdx.x;     // over H*L*N rows
    if (row >= HLN_) return;
    const f32x4* src = (const f32x4*)(sb + (size_t)row * DK_);
    float v[DK_];
#pragma unroll
    for (int i = 0; i < 8; i++) {
        f32x4 t4 = src[i];
        v[4*i+0] = t4[0]; v[4*i+1] = t4[1]; v[4*i+2] = t4[2]; v[4*i+3] = t4[3];
    }
    float m = v[0];
#pragma unroll
    for (int i = 1; i < DK_; i++) m = fmaxf(m, v[i]);
    float s = 0.f;
#pragma unroll
    for (int i = 0; i < DK_; i++) { v[i] = __expf((v[i] - m) * SCALE_); s += v[i]; }
    float inv = 1.f / s;
    f32x4* dst = (f32x4*)(ks + (size_t)row * DK_);
#pragma unroll
    for (int i = 0; i < 8; i++) {
        f32x4 t4;
        t4[0] = v[4*i+0]*inv; t4[1] = v[4*i+1]*inv; t4[2] = v[4*i+2]*inv; t4[3] = v[4*i+3]*inv;
        dst[i] = t4;
    }
}

// ---------------- K1: fused q,v conv via MFMA fp16, write [B,H,L,N,DK] fp16 --
// block: 512 thr (8 waves), tile M=512 (q256+v256) x S=96 (8n x 12l), BK=32
__global__ __launch_bounds__(512) void k_conv_qv(const float* __restrict__ x,
    const float* __restrict__ wq, const float* __restrict__ bqp,
    const float* __restrict__ wv, const float* __restrict__ bvp,
    _Float16* __restrict__ qh, _Float16* __restrict__ vh) {
    __shared__ __align__(16) char sm[50688];
    __shared__ float Bq[256], Bv[256];
    _Float16* Wqs = (_Float16*)sm;            // [256][40]
    _Float16* Wvs = (_Float16*)(sm + 20480);  // [256][40]
    _Float16* Xt  = (_Float16*)(sm + 40960);  // [96][40]
    _Float16* Ost = (_Float16*)sm;            // [96][264] (epilogue, unioned)

    const int t = threadIdx.x;
    const int bx = blockIdx.x, b = blockIdx.y;
    const int s0 = bx * 96;
    const int w = t >> 6, lane = t & 63;
    const int lo = lane & 15, hi = lane >> 4;
    const int x0 = hi * 8;

    if (t < 64) {
        *(f32x4*)&Bq[t*4] = *(const f32x4*)(bqp + t*4);
        *(f32x4*)&Bv[t*4] = *(const f32x4*)(bvp + t*4);
    }

    f32x4 acc[4][6] = {};
    const int o0 = (w & 3) * 64;
    const int ci = t & 31, j = t >> 5;        // X staging (j<12 active)
    const int so = t >> 1, kh = t & 1;        // W staging

    const float* xrow = x + (size_t)b * CNL_ + (size_t)ci * NL_ + s0 + j * 8;

    for (int kb = 0; kb < 8; ++kb) {
        const int k0 = kb * 32;
        if (j < 12) {
            const float* src = xrow + (size_t)k0 * NL_;
            f32x4 v0 = *(const f32x4*)src;
            f32x4 v1 = *(const f32x4*)(src + 4);
            const int sb = j * 8;
#pragma unroll
            for (int i = 0; i < 4; ++i) Xt[(sb+i)*40 + ci]   = (_Float16)v0[i];
#pragma unroll
            for (int i = 0; i < 4; ++i) Xt[(sb+4+i)*40 + ci] = (_Float16)v1[i];
        }
        {
            const float* srcq = wq + (size_t)so * C_ + k0 + kh*16;
            f32x4 a0 = *(const f32x4*)srcq,     a1 = *(const f32x4*)(srcq+4);
            f32x4 a2 = *(const f32x4*)(srcq+8), a3 = *(const f32x4*)(srcq+12);
            half8 h0, h1;
#pragma unroll
            for (int i = 0; i < 4; ++i) { h0[i] = (_Float16)a0[i]; h0[4+i] = (_Float16)a1[i];
                                          h1[i] = (_Float16)a2[i]; h1[4+i] = (_Float16)a3[i]; }
            *(half8*)&Wqs[so*40 + kh*16]     = h0;
            *(half8*)&Wqs[so*40 + kh*16 + 8] = h1;
            const float* srcv = wv + (size_t)so * C_ + k0 + kh*16;
            f32x4 c0 = *(const f32x4*)srcv,     c1 = *(const f32x4*)(srcv+4);
            f32x4 c2 = *(const f32x4*)(srcv+8), c3 = *(const f32x4*)(srcv+12);
            half8 g0, g1;
#pragma unroll
            for (int i = 0; i < 4; ++i) { g0[i] = (_Float16)c0[i]; g0[4+i] = (_Float16)c1[i];
                                          g1[i] = (_Float16)c2[i]; g1[4+i] = (_Float16)c3[i]; }
            *(half8*)&Wvs[so*40 + kh*16]     = g0;
            *(half8*)&Wvs[so*40 + kh*16 + 8] = g1;
        }
        __syncthreads();
        const _Float16* Ws = (w >> 2) ? Wvs : Wqs;
        half8 af[4], bf[6];
#pragma unroll
        for (int m = 0; m < 4; ++m) af[m] = *(const half8*)&Ws[(o0 + m*16 + lo)*40 + x0];
#pragma unroll
        for (int sf = 0; sf < 6; ++sf) bf[sf] = *(const half8*)&Xt[(sf*16 + lo)*40 + x0];
#pragma unroll
        for (int m = 0; m < 4; ++m)
#pragma unroll
            for (int sf = 0; sf < 6; ++sf)
                acc[m][sf] = __builtin_amdgcn_mfma_f32_16x16x32_f16(af[m], bf[sf], acc[m][sf], 0, 0, 0);
        __syncthreads();
    }
    // epilogue: pass 0 = q, pass 1 = v
    for (int pass = 0; pass < 2; ++pass) {
        if ((w >> 2) == pass) {
            const float* Bs = pass ? Bv : Bq;
#pragma unroll
            for (int m = 0; m < 4; ++m) {
                const int ow = o0 + m*16 + hi*4;
                const float b0 = Bs[ow], b1 = Bs[ow+1], b2 = Bs[ow+2], b3 = Bs[ow+3];
#pragma unroll
                for (int sf = 0; sf < 6; ++sf) {
                    const int s = sf*16 + lo;
                    half4 hh;
                    hh[0] = (_Float16)fmaxf(acc[m][sf][0] + b0, 0.f);
                    hh[1] = (_Float16)fmaxf(acc[m][sf][1] + b1, 0.f);
                    hh[2] = (_Float16)fmaxf(acc[m][sf][2] + b2, 0.f);
                    hh[3] = (_Float16)fmaxf(acc[m][sf][3] + b3, 0.f);
                    *(half4*)&Ost[s*264 + ow] = hh;
                }
            }
        }
        __syncthreads();
        _Float16* dst0 = pass ? vh : qh;
        for (int p = t; p < 768; p += 512) {
            const int s = p >> 3, hhx = p & 7;
            const int sg = s0 + s;
            const int n = div12(sg), l = sg - n*12;
            const uint4* srcv = (const uint4*)&Ost[s*264 + hhx*32];
            uint4 u0 = srcv[0], u1 = srcv[1], u2 = srcv[2], u3 = srcv[3];
            uint4* d = (uint4*)(dst0 + ((((size_t)(b*8 + hhx)*12 + l)*1024 + n)*32));
            d[0] = u0; d[1] = u1; d[2] = u2; d[3] = u3;
        }
        __syncthreads();
    }
}

// ---------------- K2: per (b,h): kv per l (VALU), softmax + P@kv (MFMA) -----
// qkv overwrites q in place.
__global__ __launch_bounds__(512) void k_attn(const float* __restrict__ ks,
    _Float16* __restrict__ q, const _Float16* __restrict__ v) {
    __shared__ __align__(16) char sm[40960];   // red f32[8*1024]  U  Pst half[512][40]
    __shared__ _Float16 kvT[32*40];
    float* red = (float*)sm;
    _Float16* Pst = (_Float16*)sm;

    const int bid = blockIdx.x;
    const int b = bid >> 3, h = bid & 7;
    const int t = threadIdx.x;
    const int w = t >> 6, lane = t & 63;
    const int lo = lane & 15, hi = lane >> 4;
    const int x0f = hi * 8;

    const float* ksh = ks + (size_t)h * 12 * ND_;
    _Float16* qb = q + ((size_t)b * 8 + h) * 12 * ND_;
    const _Float16* vb = v + ((size_t)b * 8 + h) * 12 * ND_;

    const int xg = lane & 7, yg = lane >> 3;
    const int ax0 = xg * 4, ay0 = yg * 4;

    for (int l = 0; l < 12; ++l) {
        const float*    ksl = ksh + (size_t)l * ND_;
        const _Float16* vl  = vb  + (size_t)l * ND_;
        float pa[4][4] = {};
#pragma unroll 2
        for (int n = w*128; n < w*128 + 128; ++n) {
            f32x4 kk = *(const f32x4*)(ksl + n*32 + ax0);
            half4 vv = *(const half4*)(vl + n*32 + ay0);
            float v0 = (float)vv[0], v1 = (float)vv[1], v2 = (float)vv[2], v3 = (float)vv[3];
#pragma unroll
            for (int xi = 0; xi < 4; ++xi) {
                pa[xi][0] += kk[xi]*v0; pa[xi][1] += kk[xi]*v1;
                pa[xi][2] += kk[xi]*v2; pa[xi][3] += kk[xi]*v3;
            }
        }
#pragma unroll
        for (int xi = 0; xi < 4; ++xi) {
            f32x4 r; r[0] = pa[xi][0]; r[1] = pa[xi][1]; r[2] = pa[xi][2]; r[3] = pa[xi][3];
            *(f32x4*)&red[w*1024 + (ax0+xi)*32 + ay0] = r;
        }
        __syncthreads();
#pragma unroll
        for (int e = t; e < 1024; e += 512) {
            float s = red[e] + red[e+1024] + red[e+2048] + red[e+3072]
                    + red[e+4096] + red[e+5120] + red[e+6144] + red[e+7168];
            kvT[(e & 31)*40 + (e >> 5)] = (_Float16)s;
        }
        __syncthreads();
        for (int batch = 0; batch < 2; ++batch) {
            _Float16* qrow = qb + (size_t)l*ND_ + (size_t)(batch*512 + t)*32;
            half8 hq0 = *(const half8*)qrow;
            half8 hq1 = *(const half8*)(qrow + 8);
            half8 hq2 = *(const half8*)(qrow + 16);
            half8 hq3 = *(const half8*)(qrow + 24);
            float qv[32];
#pragma unroll
            for (int i = 0; i < 8; ++i) { qv[i] = (float)hq0[i]; qv[8+i] = (float)hq1[i];
                                          qv[16+i] = (float)hq2[i]; qv[24+i] = (float)hq3[i]; }
            float m = qv[0];
#pragma unroll
            for (int i = 1; i < 32; ++i) m = fmaxf(m, qv[i]);
            float ssum = 0.f;
#pragma unroll
            for (int i = 0; i < 32; ++i) { float e = __expf((qv[i]-m)*SCALE_); qv[i] = e; ssum += e; }
            const float inv = 1.f / ssum;
            half8 ph0, ph1, ph2, ph3;
#pragma unroll
            for (int i = 0; i < 8; ++i) { ph0[i] = (_Float16)(qv[i]*inv); ph1[i] = (_Float16)(qv[8+i]*inv);
                                          ph2[i] = (_Float16)(qv[16+i]*inv); ph3[i] = (_Float16)(qv[24+i]*inv); }
            *(half8*)&Pst[t*40 + 0]  = ph0;
            *(half8*)&Pst[t*40 + 8]  = ph1;
            *(half8*)&Pst[t*40 + 16] = ph2;
            *(half8*)&Pst[t*40 + 24] = ph3;
            __syncthreads();
            f32x4 oacc[4][2] = {};
            const int wr0 = w * 64;
            half8 bb0 = *(const half8*)&kvT[(lo)*40 + x0f];
            half8 bb1 = *(const half8*)&kvT[(16 + lo)*40 + x0f];
#pragma unroll
            for (int m2 = 0; m2 < 4; ++m2) {
                half8 a = *(const half8*)&Pst[(wr0 + m2*16 + lo)*40 + x0f];
                oacc[m2][0] = __builtin_amdgcn_mfma_f32_16x16x32_f16(a, bb0, oacc[m2][0], 0, 0, 0);
                oacc[m2][1] = __builtin_amdgcn_mfma_f32_16x16x32_f16(a, bb1, oacc[m2][1], 0, 0, 0);
            }
            __syncthreads();
#pragma unroll
            for (int m2 = 0; m2 < 4; ++m2)
#pragma unroll
                for (int yf = 0; yf < 2; ++yf)
#pragma unroll
                    for (int i = 0; i < 4; ++i)
                        Pst[(wr0 + m2*16 + hi*4 + i)*40 + yf*16 + lo] = (_Float16)oacc[m2][yf][i];
            __syncthreads();
            {
                const uint4* s4 = (const uint4*)&Pst[t*40];
                uint4 a0 = s4[0], a1 = s4[1], a2 = s4[2], a3 = s4[3];
                uint4* d = (uint4*)qrow;
                d[0] = a0; d[1] = a1; d[2] = a2; d[3] = a3;
            }
            __syncthreads();
        }
    }
}

// ---------------- K3: final conv via MFMA fp16 from qkv[b,h,l,n,y] -> fp32 ---
__global__ __launch_bounds__(512) void k_conv_out(const _Float16* __restrict__ qkv,
    const float* __restrict__ cw, const float* __restrict__ cbp, float* __restrict__ out) {
    __shared__ __align__(16) char sm[51200];
    __shared__ float Cb[256];
    _Float16* Ws = (_Float16*)sm;             // [256][40]
    _Float16* Xt = (_Float16*)(sm + 20480);   // [96][40]
    float*    St = (float*)sm;                // [128][100] epilogue (unioned)

    const int t = threadIdx.x;
    const int bx = blockIdx.x, b = blockIdx.y;
    const int s0 = bx * 96;
    const int w = t >> 6, lane = t & 63;
    const int lo = lane & 15, hi = lane >> 4;
    const int x0 = hi * 8;
    if (t < 64) *(f32x4*)&Cb[t*4] = *(const f32x4*)(cbp + t*4);

    const int o0w = (w >> 1) * 64, s0w = (w & 1) * 48;
    f32x4 acc[4][3] = {};
    const int so = t >> 1, kh = t & 1;
    const int sx = t >> 2, oct = t & 3;
    // hoisted X staging address pieces (t<384)
    int xn = 0, xl = 0;
    if (t < 384) { int sg = s0 + sx; xn = div12(sg); xl = sg - xn*12; }
    const _Float16* xbase = qkv + (((size_t)b*8)*12 + xl)*(size_t)ND_ + (size_t)xn*32 + oct*8;

    for (int kb = 0; kb < 8; ++kb) {
        {
            const float* src = cw + (size_t)so * C_ + kb*32 + kh*16;
            f32x4 a0 = *(const f32x4*)src,     a1 = *(const f32x4*)(src+4);
            f32x4 a2 = *(const f32x4*)(src+8), a3 = *(const f32x4*)(src+12);
            half8 h0, h1;
#pragma unroll
            for (int i = 0; i < 4; ++i) { h0[i] = (_Float16)a0[i]; h0[4+i] = (_Float16)a1[i];
                                          h1[i] = (_Float16)a2[i]; h1[4+i] = (_Float16)a3[i]; }
            *(half8*)&Ws[so*40 + kh*16]     = h0;
            *(half8*)&Ws[so*40 + kh*16 + 8] = h1;
        }
        if (t < 384) {
            const uint4 u = *(const uint4*)(xbase + (size_t)kb * 12 * ND_);
            *(uint4*)&Xt[sx*40 + oct*8] = u;
        }
        __syncthreads();
        half8 af[4], bf[3];
#pragma unroll
        for (int m = 0; m < 4; ++m) af[m] = *(const half8*)&Ws[(o0w + m*16 + lo)*40 + x0];
#pragma unroll
        for (int sf = 0; sf < 3; ++sf) bf[sf] = *(const half8*)&Xt[(s0w + sf*16 + lo)*40 + x0];
#pragma unroll
        for (int m = 0; m < 4; ++m)
#pragma unroll
            for (int sf = 0; sf < 3; ++sf)
                acc[m][sf] = __builtin_amdgcn_mfma_f32_16x16x32_f16(af[m], bf[sf], acc[m][sf], 0, 0, 0);
        __syncthreads();
    }
    for (int ph = 0; ph < 2; ++ph) {
        if ((w >> 2) == ph) {
#pragma unroll
            for (int m = 0; m < 4; ++m) {
                const int ow = o0w + m*16 + hi*4;
                const int ro = ow - ph*128;
#pragma unroll
                for (int sf = 0; sf < 3; ++sf) {
                    const int s = s0w + sf*16 + lo;
#pragma unroll
                    for (int i = 0; i < 4; ++i)
                        St[(ro+i)*100 + s] = fmaxf(acc[m][sf][i] + Cb[ow+i], 0.f);
                }
            }
        }
        __syncthreads();
        {
            const int ol = t >> 2, sq = t & 3;
            const int o = ph*128 + ol;
            const int sg = s0 + sq*24;
            const int n0 = sg / 12;   // exact (sg multiple of 12)
            float* dst = out + ((size_t)(b*256 + o)*1024 + n0)*12;
            const f32x4* srcv = (const f32x4*)&St[ol*100 + sq*24];
#pragma unroll
            for (int i2 = 0; i2 < 6; ++i2) *(f32x4*)(dst + i2*4) = srcv[i2];
        }
        __syncthreads();
    }
}

extern "C" void kernel_launch(void* const* d_in, const int* in_sizes, int n_in,
                              void* d_out, int out_size, void* d_ws, size_t ws_size,
                              hipStream_t stream) {
    const float* input = (const float*)d_in[0];
    const float* q_w   = (const float*)d_in[1];
    const float* q_b   = (const float*)d_in[2];
    const float* v_w   = (const float*)d_in[3];
    const float* v_b   = (const float*)d_in[4];
    const float* c_w   = (const float*)d_in[5];
    const float* c_b   = (const float*)d_in[6];
    const float* s_bank= (const float*)d_in[7];
    float* out = (float*)d_out;

    char* ws = (char*)d_ws;
    float*     ks = (float*)ws;                                  // 3,145,728 f32 = 12.58 MB
    _Float16*  qh = (_Float16*)(ws + (size_t)HLN_*DK_*4);        // 100,663,296 half = 201 MB
    _Float16*  vh = qh + (size_t)B_*HLN_*DK_;                    // 201 MB

    k_key_softmax<<<dim3((HLN_ + 255)/256), dim3(256), 0, stream>>>(s_bank, ks);
    k_conv_qv<<<dim3(128, 32), dim3(512), 0, stream>>>(input, q_w, q_b, v_w, v_b, qh, vh);
    k_attn<<<dim3(B_ * H_), dim3(512), 0, stream>>>(ks, qh, vh);
    k_conv_out<<<dim3(128, 32), dim3(512), 0, stream>>>(qh, c_w, c_b, out);
}

// Round 3
// 1002.201 us; speedup vs baseline: 2.4219x; 1.2197x over previous
//
#include <hip/hip_runtime.h>

#define B_   32
#define C_   256
#define N_   1024
#define L_   12
#define H_   8
#define DK_  32
#define NL_  12288
#define CNL_ 3145728
#define ND_  32768
#define HLN_ 98304
#define SCALE_ 0.17677669529663687f

typedef _Float16 half8 __attribute__((ext_vector_type(8)));
typedef _Float16 half4 __attribute__((ext_vector_type(4)));
typedef float f32x4 __attribute__((ext_vector_type(4)));

__device__ __forceinline__ int div12(int s) { return (int)(((unsigned)s * 43691u) >> 19); }

// ---------------- K0: softmax over DK of s_bank * scale -> ks (fp16) --------
__global__ __launch_bounds__(256) void k_key_softmax(const float* __restrict__ sb,
                                                     _Float16* __restrict__ ks) {
    int row = blockIdx.x * 256 + threadIdx.x;     // over H*L*N rows
    if (row >= HLN_) return;
    const f32x4* src = (const f32x4*)(sb + (size_t)row * DK_);
    float v[DK_];
#pragma unroll
    for (int i = 0; i < 8; i++) {
        f32x4 t4 = src[i];
        v[4*i+0] = t4[0]; v[4*i+1] = t4[1]; v[4*i+2] = t4[2]; v[4*i+3] = t4[3];
    }
    float m = v[0];
#pragma unroll
    for (int i = 1; i < DK_; i++) m = fmaxf(m, v[i]);
    float s = 0.f;
#pragma unroll
    for (int i = 0; i < DK_; i++) { v[i] = __expf((v[i] - m) * SCALE_); s += v[i]; }
    float inv = 1.f / s;
    half8* dst = (half8*)(ks + (size_t)row * DK_);
#pragma unroll
    for (int i = 0; i < 4; i++) {
        half8 t8;
#pragma unroll
        for (int j = 0; j < 8; j++) t8[j] = (_Float16)(v[i*8+j] * inv);
        dst[i] = t8;
    }
}

// ---------------- K1: fused q,v conv via MFMA fp16, write [B,H,L,N,DK] fp16 --
// block: 512 thr (8 waves), tile M=512 (q256+v256) x S=96 (8n x 12l), BK=32
__global__ __launch_bounds__(512) void k_conv_qv(const float* __restrict__ x,
    const float* __restrict__ wq, const float* __restrict__ bqp,
    const float* __restrict__ wv, const float* __restrict__ bvp,
    _Float16* __restrict__ qh, _Float16* __restrict__ vh) {
    __shared__ __align__(16) char sm[50688];
    __shared__ float Bq[256], Bv[256];
    _Float16* Wqs = (_Float16*)sm;            // [256][40]
    _Float16* Wvs = (_Float16*)(sm + 20480);  // [256][40]
    _Float16* Xt  = (_Float16*)(sm + 40960);  // [96][40]
    _Float16* Ost = (_Float16*)sm;            // [96][264] (epilogue, unioned)

    const int t = threadIdx.x;
    const int bx = blockIdx.x, b = blockIdx.y;
    const int s0 = bx * 96;
    const int w = t >> 6, lane = t & 63;
    const int lo = lane & 15, hi = lane >> 4;
    const int x0 = hi * 8;

    if (t < 64) {
        *(f32x4*)&Bq[t*4] = *(const f32x4*)(bqp + t*4);
        *(f32x4*)&Bv[t*4] = *(const f32x4*)(bvp + t*4);
    }

    f32x4 acc[4][6] = {};
    const int o0 = (w & 3) * 64;
    const int ci = t & 31, j = t >> 5;        // X staging (j<12 active)
    const int so = t >> 1, kh = t & 1;        // W staging

    const float* xrow = x + (size_t)b * CNL_ + (size_t)ci * NL_ + s0 + j * 8;

    for (int kb = 0; kb < 8; ++kb) {
        const int k0 = kb * 32;
        if (j < 12) {
            const float* src = xrow + (size_t)k0 * NL_;
            f32x4 v0 = *(const f32x4*)src;
            f32x4 v1 = *(const f32x4*)(src + 4);
            const int sb = j * 8;
#pragma unroll
            for (int i = 0; i < 4; ++i) Xt[(sb+i)*40 + ci]   = (_Float16)v0[i];
#pragma unroll
            for (int i = 0; i < 4; ++i) Xt[(sb+4+i)*40 + ci] = (_Float16)v1[i];
        }
        {
            const float* srcq = wq + (size_t)so * C_ + k0 + kh*16;
            f32x4 a0 = *(const f32x4*)srcq,     a1 = *(const f32x4*)(srcq+4);
            f32x4 a2 = *(const f32x4*)(srcq+8), a3 = *(const f32x4*)(srcq+12);
            half8 h0, h1;
#pragma unroll
            for (int i = 0; i < 4; ++i) { h0[i] = (_Float16)a0[i]; h0[4+i] = (_Float16)a1[i];
                                          h1[i] = (_Float16)a2[i]; h1[4+i] = (_Float16)a3[i]; }
            *(half8*)&Wqs[so*40 + kh*16]     = h0;
            *(half8*)&Wqs[so*40 + kh*16 + 8] = h1;
            const float* srcv = wv + (size_t)so * C_ + k0 + kh*16;
            f32x4 c0 = *(const f32x4*)srcv,     c1 = *(const f32x4*)(srcv+4);
            f32x4 c2 = *(const f32x4*)(srcv+8), c3 = *(const f32x4*)(srcv+12);
            half8 g0, g1;
#pragma unroll
            for (int i = 0; i < 4; ++i) { g0[i] = (_Float16)c0[i]; g0[4+i] = (_Float16)c1[i];
                                          g1[i] = (_Float16)c2[i]; g1[4+i] = (_Float16)c3[i]; }
            *(half8*)&Wvs[so*40 + kh*16]     = g0;
            *(half8*)&Wvs[so*40 + kh*16 + 8] = g1;
        }
        __syncthreads();
        const _Float16* Ws = (w >> 2) ? Wvs : Wqs;
        half8 af[4], bf[6];
#pragma unroll
        for (int m = 0; m < 4; ++m) af[m] = *(const half8*)&Ws[(o0 + m*16 + lo)*40 + x0];
#pragma unroll
        for (int sf = 0; sf < 6; ++sf) bf[sf] = *(const half8*)&Xt[(sf*16 + lo)*40 + x0];
#pragma unroll
        for (int m = 0; m < 4; ++m)
#pragma unroll
            for (int sf = 0; sf < 6; ++sf)
                acc[m][sf] = __builtin_amdgcn_mfma_f32_16x16x32_f16(af[m], bf[sf], acc[m][sf], 0, 0, 0);
        __syncthreads();
    }
    // epilogue: pass 0 = q, pass 1 = v
    for (int pass = 0; pass < 2; ++pass) {
        if ((w >> 2) == pass) {
            const float* Bs = pass ? Bv : Bq;
#pragma unroll
            for (int m = 0; m < 4; ++m) {
                const int ow = o0 + m*16 + hi*4;
                const float b0 = Bs[ow], b1 = Bs[ow+1], b2 = Bs[ow+2], b3 = Bs[ow+3];
#pragma unroll
                for (int sf = 0; sf < 6; ++sf) {
                    const int s = sf*16 + lo;
                    half4 hh;
                    hh[0] = (_Float16)fmaxf(acc[m][sf][0] + b0, 0.f);
                    hh[1] = (_Float16)fmaxf(acc[m][sf][1] + b1, 0.f);
                    hh[2] = (_Float16)fmaxf(acc[m][sf][2] + b2, 0.f);
                    hh[3] = (_Float16)fmaxf(acc[m][sf][3] + b3, 0.f);
                    *(half4*)&Ost[s*264 + ow] = hh;
                }
            }
        }
        __syncthreads();
        _Float16* dst0 = pass ? vh : qh;
        for (int p = t; p < 768; p += 512) {
            const int s = p >> 3, hhx = p & 7;
            const int sg = s0 + s;
            const int n = div12(sg), l = sg - n*12;
            const uint4* srcv = (const uint4*)&Ost[s*264 + hhx*32];
            uint4 u0 = srcv[0], u1 = srcv[1], u2 = srcv[2], u3 = srcv[3];
            uint4* d = (uint4*)(dst0 + ((((size_t)(b*8 + hhx)*12 + l)*1024 + n)*32));
            d[0] = u0; d[1] = u1; d[2] = u2; d[3] = u3;
        }
        __syncthreads();
    }
}

// ---------------- K2: kvT[b,h,l][y][x] = sum_n V[n][y] * K[n][x]  (fp16 out) -
__global__ __launch_bounds__(256) void k_kv(const _Float16* __restrict__ ks,
    const _Float16* __restrict__ v, _Float16* __restrict__ kvT) {
    __shared__ float red[4096];
    const int bid = blockIdx.x;            // (b*8+h)*12 + l
    const int bh = bid / 12;
    const int l  = bid - bh * 12;
    const int h  = bh & 7;
    const int t = threadIdx.x, w = t >> 6, lane = t & 63;
    const int xg = lane & 7, yg = lane >> 3;
    const _Float16* kp = ks + ((size_t)(h*12 + l)*1024 + w*256)*32 + xg*4;
    const _Float16* vp = v  + ((size_t)(bh*12 + l)*1024 + w*256)*32 + yg*4;
    float pa[4][4] = {};
#pragma unroll 4
    for (int n = 0; n < 256; ++n) {
        half4 kk = *(const half4*)(kp + n*32);
        half4 vv = *(const half4*)(vp + n*32);
        float k0=(float)kk[0], k1=(float)kk[1], k2=(float)kk[2], k3=(float)kk[3];
        float v0=(float)vv[0], v1=(float)vv[1], v2=(float)vv[2], v3=(float)vv[3];
        pa[0][0] += k0*v0; pa[0][1] += k0*v1; pa[0][2] += k0*v2; pa[0][3] += k0*v3;
        pa[1][0] += k1*v0; pa[1][1] += k1*v1; pa[1][2] += k1*v2; pa[1][3] += k1*v3;
        pa[2][0] += k2*v0; pa[2][1] += k2*v1; pa[2][2] += k2*v2; pa[2][3] += k2*v3;
        pa[3][0] += k3*v0; pa[3][1] += k3*v1; pa[3][2] += k3*v2; pa[3][3] += k3*v3;
    }
    // store partials already transposed: red[w][y][x]
#pragma unroll
    for (int xi = 0; xi < 4; ++xi)
#pragma unroll
        for (int yi = 0; yi < 4; ++yi)
            red[w*1024 + (yg*4 + yi)*32 + xg*4 + xi] = pa[xi][yi];
    __syncthreads();
    const int e = t * 4;
    f32x4 s = *(const f32x4*)&red[e];
    s += *(const f32x4*)&red[1024 + e];
    s += *(const f32x4*)&red[2048 + e];
    s += *(const f32x4*)&red[3072 + e];
    half4 o;
#pragma unroll
    for (int i = 0; i < 4; ++i) o[i] = (_Float16)s[i];
    *(half4*)(kvT + (size_t)bid * 1024 + e) = o;
}

// ---- K3: fused softmax(q)@kvT (MFMA) + final conv (MFMA) -> relu -> out ----
__global__ __launch_bounds__(512, 4) void k_conv_out(
    const _Float16* __restrict__ q, const _Float16* __restrict__ kvw,
    const float* __restrict__ cw, const float* __restrict__ cbp,
    float* __restrict__ out) {
    __shared__ __align__(16) char sm[52736];
    __shared__ float Cb[256];
    _Float16* Ws  = (_Float16*)sm;              // [256][40] fp16
    _Float16* Xt  = (_Float16*)(sm + 20480);    // [96][40] fp16 (qkv tile)
    _Float16* kvs = (_Float16*)(sm + 28160);    // [12][32][32] fp16 (kvT per head)
    float*    St  = (float*)sm;                 // [128][100] f32 epilogue (overlay)

    const int t = threadIdx.x;
    const int bx = blockIdx.x, b = blockIdx.y;
    const int s0 = bx * 96;
    const int n0 = bx * 8;
    const int w = t >> 6, lane = t & 63;
    const int lo = lane & 15, hi = lane >> 4;
    const int x0 = hi * 8;
    if (t < 64) *(f32x4*)&Cb[t*4] = *(const f32x4*)(cbp + t*4);

    const int o0w = (w >> 1) * 64, s0w = (w & 1) * 48;
    f32x4 acc[4][3] = {};
    const int so = t >> 1, kh = t & 1;          // W staging

    // PV: waves 0..5, each owns 2 l values
    const bool pvw = (w < 6);
    const int li0 = w * 2;
    const int qrow = n0 + (lo & 7);             // duplicate rows 8..15 onto 0..7 (masked)
    const float rowmask = (lo < 8) ? 1.f : 0.f;
    const size_t hstep = (size_t)12 * ND_;      // per-head stride in q
    const _Float16* qb_b = q + (size_t)b * 8 * hstep;

    half8 hq0 = {}, hq1 = {};
    if (pvw) {
        hq0 = *(const half8*)(qb_b + (size_t)li0 * ND_ + (size_t)qrow*32 + hi*8);
        hq1 = *(const half8*)(qb_b + (size_t)(li0+1) * ND_ + (size_t)qrow*32 + hi*8);
    }

    for (int kb = 0; kb < 8; ++kb) {
        // stage W tile (fp32 -> fp16, transposed-free layout [o][k])
        {
            const float* src = cw + (size_t)so * C_ + kb*32 + kh*16;
            f32x4 a0 = *(const f32x4*)src,     a1 = *(const f32x4*)(src+4);
            f32x4 a2 = *(const f32x4*)(src+8), a3 = *(const f32x4*)(src+12);
            half8 h0, h1;
#pragma unroll
            for (int i = 0; i < 4; ++i) { h0[i] = (_Float16)a0[i]; h0[4+i] = (_Float16)a1[i];
                                          h1[i] = (_Float16)a2[i]; h1[4+i] = (_Float16)a3[i]; }
            *(half8*)&Ws[so*40 + kh*16]     = h0;
            *(half8*)&Ws[so*40 + kh*16 + 8] = h1;
        }
        // stage kvT for this (b, head): 12288 halfs linear
        {
            const _Float16* kvg = kvw + ((size_t)(b*8 + kb)*12) * 1024;
#pragma unroll
            for (int i = 0; i < 3; ++i) {
                const int c = t + i*512;
                *(half8*)&kvs[c*8] = *(const half8*)(kvg + c*8);
            }
        }
        __syncthreads();
        // PV phase: softmax in-fragment + 2 MFMAs per l -> Xt
        if (pvw) {
            half8 nq0 = hq0, nq1 = hq1;
            if (kb < 7) {
                nq0 = *(const half8*)(qb_b + (kb+1)*hstep + (size_t)li0 * ND_ + (size_t)qrow*32 + hi*8);
                nq1 = *(const half8*)(qb_b + (kb+1)*hstep + (size_t)(li0+1) * ND_ + (size_t)qrow*32 + hi*8);
            }
#pragma unroll
            for (int sub = 0; sub < 2; ++sub) {
                const half8 hq = sub ? hq1 : hq0;
                const int li = li0 + sub;
                float qv[8];
#pragma unroll
                for (int i = 0; i < 8; ++i) qv[i] = (float)hq[i];
                float m8 = fmaxf(fmaxf(fmaxf(qv[0], qv[1]), fmaxf(qv[2], qv[3])),
                                 fmaxf(fmaxf(qv[4], qv[5]), fmaxf(qv[6], qv[7])));
                m8 = fmaxf(m8, __shfl_xor(m8, 16));
                m8 = fmaxf(m8, __shfl_xor(m8, 32));
                const float mS = m8 * SCALE_;
                float ex[8]; float ssum = 0.f;
#pragma unroll
                for (int i = 0; i < 8; ++i) { ex[i] = __expf(qv[i]*SCALE_ - mS); ssum += ex[i]; }
                ssum += __shfl_xor(ssum, 16);
                ssum += __shfl_xor(ssum, 32);
                const float pin = rowmask / ssum;
                half8 af;
#pragma unroll
                for (int i = 0; i < 8; ++i) af[i] = (_Float16)(ex[i] * pin);
                const half8 b0 = *(const half8*)&kvs[li*1024 + lo*32 + hi*8];
                const half8 b1 = *(const half8*)&kvs[li*1024 + (16+lo)*32 + hi*8];
                f32x4 d0 = {}, d1 = {};
                d0 = __builtin_amdgcn_mfma_f32_16x16x32_f16(af, b0, d0, 0, 0, 0);
                d1 = __builtin_amdgcn_mfma_f32_16x16x32_f16(af, b1, d1, 0, 0, 0);
                if (hi < 2) {
#pragma unroll
                    for (int reg = 0; reg < 4; ++reg) {
                        const int srow = (hi*4 + reg)*12 + li;
                        Xt[srow*40 + lo]      = (_Float16)d0[reg];
                        Xt[srow*40 + 16 + lo] = (_Float16)d1[reg];
                    }
                }
            }
            hq0 = nq0; hq1 = nq1;
        }
        __syncthreads();
        // conv MFMA
        half8 af2[4], bf[3];
#pragma unroll
        for (int m = 0; m < 4; ++m) af2[m] = *(const half8*)&Ws[(o0w + m*16 + lo)*40 + x0];
#pragma unroll
        for (int sf = 0; sf < 3; ++sf) bf[sf] = *(const half8*)&Xt[(s0w + sf*16 + lo)*40 + x0];
#pragma unroll
        for (int m = 0; m < 4; ++m)
#pragma unroll
            for (int sf = 0; sf < 3; ++sf)
                acc[m][sf] = __builtin_amdgcn_mfma_f32_16x16x32_f16(af2[m], bf[sf], acc[m][sf], 0, 0, 0);
        __syncthreads();
    }
    // epilogue: bias + relu, stage f32 in LDS, coalesced out writes
    for (int ph = 0; ph < 2; ++ph) {
        if ((w >> 2) == ph) {
#pragma unroll
            for (int m = 0; m < 4; ++m) {
                const int ow = o0w + m*16 + hi*4;
                const int ro = ow - ph*128;
#pragma unroll
                for (int sf = 0; sf < 3; ++sf) {
                    const int s = s0w + sf*16 + lo;
#pragma unroll
                    for (int i = 0; i < 4; ++i)
                        St[(ro+i)*100 + s] = fmaxf(acc[m][sf][i] + Cb[ow+i], 0.f);
                }
            }
        }
        __syncthreads();
        {
            const int ol = t >> 2, sq = t & 3;
            const int o = ph*128 + ol;
            const int sg = s0 + sq*24;
            const int n0e = sg / 12;   // exact (sg multiple of 12)
            float* dst = out + ((size_t)(b*256 + o)*1024 + n0e)*12;
            const f32x4* srcv = (const f32x4*)&St[ol*100 + sq*24];
#pragma unroll
            for (int i2 = 0; i2 < 6; ++i2) *(f32x4*)(dst + i2*4) = srcv[i2];
        }
        __syncthreads();
    }
}

extern "C" void kernel_launch(void* const* d_in, const int* in_sizes, int n_in,
                              void* d_out, int out_size, void* d_ws, size_t ws_size,
                              hipStream_t stream) {
    const float* input = (const float*)d_in[0];
    const float* q_w   = (const float*)d_in[1];
    const float* q_b   = (const float*)d_in[2];
    const float* v_w   = (const float*)d_in[3];
    const float* v_b   = (const float*)d_in[4];
    const float* c_w   = (const float*)d_in[5];
    const float* c_b   = (const float*)d_in[6];
    const float* s_bank= (const float*)d_in[7];
    float* out = (float*)d_out;

    char* ws = (char*)d_ws;
    _Float16* ks16 = (_Float16*)ws;                          // 6,291,456 B
    _Float16* qh   = (_Float16*)(ws + 6291456);              // 201,326,592 B
    _Float16* vh   = qh + (size_t)100663296;                 // 201,326,592 B
    _Float16* kvT  = vh + (size_t)100663296;                 // 6,291,456 B

    k_key_softmax<<<dim3((HLN_ + 255)/256), dim3(256), 0, stream>>>(s_bank, ks16);
    k_conv_qv<<<dim3(128, 32), dim3(512), 0, stream>>>(input, q_w, q_b, v_w, v_b, qh, vh);
    k_kv<<<dim3(B_ * H_ * L_), dim3(256), 0, stream>>>(ks16, vh, kvT);
    k_conv_out<<<dim3(128, 32), dim3(512), 0, stream>>>(qh, kvT, c_w, c_b, out);
}

// Round 4
// 887.258 us; speedup vs baseline: 2.7356x; 1.1295x over previous
//
#include <hip/hip_runtime.h>

#define B_   32
#define C_   256
#define N_   1024
#define L_   12
#define H_   8
#define DK_  32
#define NL_  12288
#define CNL_ 3145728
#define ND_  32768
#define HLN_ 98304
#define SCALE_ 0.17677669529663687f

typedef _Float16 half8 __attribute__((ext_vector_type(8)));
typedef _Float16 half4 __attribute__((ext_vector_type(4)));
typedef float f32x4 __attribute__((ext_vector_type(4)));

__device__ __forceinline__ int div12(int s) { return (int)(((unsigned)s * 43691u) >> 19); }

__device__ __forceinline__ void load_lds16(const _Float16* g, _Float16* l) {
    __builtin_amdgcn_global_load_lds(
        (const __attribute__((address_space(1))) void*)(const void*)g,
        (__attribute__((address_space(3))) void*)(void*)l, 16, 0, 0);
}

// ---------------- P: one-time fp32 -> fp16 weight conversion ----------------
__global__ __launch_bounds__(256) void k_prep(const float* __restrict__ wq,
    const float* __restrict__ wv, const float* __restrict__ cw,
    _Float16* __restrict__ W16, _Float16* __restrict__ C16) {
    const int i4 = (blockIdx.x * 256 + threadIdx.x) * 4;   // grid 64 -> 65536 elems
    f32x4 a = *(const f32x4*)(wq + i4);
    f32x4 b = *(const f32x4*)(wv + i4);
    f32x4 c = *(const f32x4*)(cw + i4);
    half4 ha, hb, hc;
#pragma unroll
    for (int i = 0; i < 4; ++i) { ha[i] = (_Float16)a[i]; hb[i] = (_Float16)b[i]; hc[i] = (_Float16)c[i]; }
    *(half4*)(W16 + i4) = ha;
    *(half4*)(W16 + 65536 + i4) = hb;
    *(half4*)(C16 + i4) = hc;
}

// ---------------- K0: softmax over DK of s_bank * scale -> ks (fp16) --------
__global__ __launch_bounds__(256) void k_key_softmax(const float* __restrict__ sb,
                                                     _Float16* __restrict__ ks) {
    int row = blockIdx.x * 256 + threadIdx.x;
    if (row >= HLN_) return;
    const f32x4* src = (const f32x4*)(sb + (size_t)row * DK_);
    float v[DK_];
#pragma unroll
    for (int i = 0; i < 8; i++) {
        f32x4 t4 = src[i];
        v[4*i+0] = t4[0]; v[4*i+1] = t4[1]; v[4*i+2] = t4[2]; v[4*i+3] = t4[3];
    }
    float m = v[0];
#pragma unroll
    for (int i = 1; i < DK_; i++) m = fmaxf(m, v[i]);
    float s = 0.f;
#pragma unroll
    for (int i = 0; i < DK_; i++) { v[i] = __expf((v[i] - m) * SCALE_); s += v[i]; }
    float inv = 1.f / s;
    half8* dst = (half8*)(ks + (size_t)row * DK_);
#pragma unroll
    for (int i = 0; i < 4; i++) {
        half8 t8;
#pragma unroll
        for (int j = 0; j < 8; j++) t8[j] = (_Float16)(v[i*8+j] * inv);
        dst[i] = t8;
    }
}

// ---------------- K1: fused q,v conv via MFMA fp16, lds-direct W staging -----
// 512 thr, tile M=512 (q256+v256) x S=96, BK=32, W/X double-buffered, 1 barrier/step
__global__ __launch_bounds__(512) void k_conv_qv(const float* __restrict__ x,
    const _Float16* __restrict__ W16,
    const float* __restrict__ bqp, const float* __restrict__ bvp,
    _Float16* __restrict__ qh, _Float16* __restrict__ vh) {
    __shared__ __align__(16) char sm[77824];
    __shared__ float Bq[256], Bv[256];
    _Float16* Wb  = (_Float16*)sm;              // [2][512][32]
    _Float16* Xb  = (_Float16*)(sm + 65536);    // [2][96][32]
    _Float16* Ost = (_Float16*)sm;              // [96][264] epilogue overlay

    const int t = threadIdx.x;
    const int bx = blockIdx.x, b = blockIdx.y;
    const int s0 = bx * 96;
    const int w = t >> 6, lane = t & 63;
    const int lo = lane & 15, hi = lane >> 4;
    const int x0 = hi * 8;

    if (t < 64) {
        *(f32x4*)&Bq[t*4] = *(const f32x4*)(bqp + t*4);
        *(f32x4*)&Bv[t*4] = *(const f32x4*)(bvp + t*4);
    }

    f32x4 acc[4][6] = {};
    const int arow = (w >> 2) * 256 + (w & 3) * 64;     // A-frag base row
    const int ci = t & 31, j = t >> 5;                  // X staging (j<12 active)
    const bool xact = (j < 12);

    // W lds-direct mapping: round r covers rows r*128 + w*16 + (lane>>2)
    const _Float16* wsrcT = W16 + ((size_t)(w*16 + (lane>>2))) * 256 + (lane & 3) * 8;
    _Float16* wdst = Wb + w * 512;                       // + buf*16384 + r*4096

    const float* xrow = x + (size_t)b * CNL_ + (size_t)ci * NL_ + s0 + j * 8;

    // ---- prologue: stage step 0 into buf 0 ----
#pragma unroll
    for (int r = 0; r < 4; ++r) load_lds16(wsrcT + r * 32768, wdst + r * 4096);
    if (xact) {
        f32x4 v0 = *(const f32x4*)xrow;
        f32x4 v1 = *(const f32x4*)(xrow + 4);
        const int sb = j * 8;
#pragma unroll
        for (int i = 0; i < 4; ++i) Xb[(sb+i)*32 + ci]   = (_Float16)v0[i];
#pragma unroll
        for (int i = 0; i < 4; ++i) Xb[(sb+4+i)*32 + ci] = (_Float16)v1[i];
    }
    __syncthreads();

    for (int kb = 0; kb < 8; ++kb) {
        const int cur = kb & 1, nxt = cur ^ 1;
        // issue next W tile (lds-direct) and next X loads (regs)
        if (kb < 7) {
            const _Float16* wsn = wsrcT + (kb + 1) * 32;
#pragma unroll
            for (int r = 0; r < 4; ++r)
                load_lds16(wsn + r * 32768, Wb + nxt*16384 + w*512 + r*4096);
        }
        f32x4 nx0, nx1;
        if (kb < 7 && xact) {
            const float* srcn = xrow + (size_t)(kb + 1) * 32 * NL_;
            nx0 = *(const f32x4*)srcn;
            nx1 = *(const f32x4*)(srcn + 4);
        }
        // fragments + MFMA
        const _Float16* Wc = Wb + cur * 16384;
        const _Float16* Xc = Xb + cur * 3072;
        half8 af[4], bf[6];
#pragma unroll
        for (int m = 0; m < 4; ++m) af[m] = *(const half8*)&Wc[(arow + m*16 + lo)*32 + x0];
#pragma unroll
        for (int sf = 0; sf < 6; ++sf) bf[sf] = *(const half8*)&Xc[(sf*16 + lo)*32 + x0];
#pragma unroll
        for (int m = 0; m < 4; ++m)
#pragma unroll
            for (int sf = 0; sf < 6; ++sf)
                acc[m][sf] = __builtin_amdgcn_mfma_f32_16x16x32_f16(af[m], bf[sf], acc[m][sf], 0, 0, 0);
        // write next X tile
        if (kb < 7 && xact) {
            _Float16* xd = Xb + nxt * 3072;
            const int sb = j * 8;
#pragma unroll
            for (int i = 0; i < 4; ++i) xd[(sb+i)*32 + ci]   = (_Float16)nx0[i];
#pragma unroll
            for (int i = 0; i < 4; ++i) xd[(sb+4+i)*32 + ci] = (_Float16)nx1[i];
        }
        __syncthreads();
    }

    // ---- epilogue: pass 0 = q, pass 1 = v ----
    const int o0 = (w & 3) * 64;
    for (int pass = 0; pass < 2; ++pass) {
        if ((w >> 2) == pass) {
            const float* Bs = pass ? Bv : Bq;
#pragma unroll
            for (int m = 0; m < 4; ++m) {
                const int ow = o0 + m*16 + hi*4;
                const float b0 = Bs[ow], b1 = Bs[ow+1], b2 = Bs[ow+2], b3 = Bs[ow+3];
#pragma unroll
                for (int sf = 0; sf < 6; ++sf) {
                    const int s = sf*16 + lo;
                    half4 hh;
                    hh[0] = (_Float16)fmaxf(acc[m][sf][0] + b0, 0.f);
                    hh[1] = (_Float16)fmaxf(acc[m][sf][1] + b1, 0.f);
                    hh[2] = (_Float16)fmaxf(acc[m][sf][2] + b2, 0.f);
                    hh[3] = (_Float16)fmaxf(acc[m][sf][3] + b3, 0.f);
                    *(half4*)&Ost[s*264 + ow] = hh;
                }
            }
        }
        __syncthreads();
        _Float16* dst0 = pass ? vh : qh;
        for (int p = t; p < 768; p += 512) {
            const int s = p >> 3, hhx = p & 7;
            const int sg = s0 + s;
            const int n = div12(sg), l = sg - n*12;
            const uint4* srcv = (const uint4*)&Ost[s*264 + hhx*32];
            uint4 u0 = srcv[0], u1 = srcv[1], u2 = srcv[2], u3 = srcv[3];
            uint4* d = (uint4*)(dst0 + ((((size_t)(b*8 + hhx)*12 + l)*1024 + n)*32));
            d[0] = u0; d[1] = u1; d[2] = u2; d[3] = u3;
        }
        __syncthreads();
    }
}

// ---------------- K2: kvT[b,h,l][y][x] = sum_n V[n][y] * K[n][x]  (fp16 out) -
__global__ __launch_bounds__(256) void k_kv(const _Float16* __restrict__ ks,
    const _Float16* __restrict__ v, _Float16* __restrict__ kvT) {
    __shared__ float red[4096];
    const int bid = blockIdx.x;            // (b*8+h)*12 + l
    const int bh = bid / 12;
    const int l  = bid - bh * 12;
    const int h  = bh & 7;
    const int t = threadIdx.x, w = t >> 6, lane = t & 63;
    const int xg = lane & 7, yg = lane >> 3;
    const _Float16* kp = ks + ((size_t)(h*12 + l)*1024 + w*256)*32 + xg*4;
    const _Float16* vp = v  + ((size_t)(bh*12 + l)*1024 + w*256)*32 + yg*4;
    float pa[4][4] = {};
#pragma unroll 4
    for (int n = 0; n < 256; ++n) {
        half4 kk = *(const half4*)(kp + n*32);
        half4 vv = *(const half4*)(vp + n*32);
        float k0=(float)kk[0], k1=(float)kk[1], k2=(float)kk[2], k3=(float)kk[3];
        float v0=(float)vv[0], v1=(float)vv[1], v2=(float)vv[2], v3=(float)vv[3];
        pa[0][0] += k0*v0; pa[0][1] += k0*v1; pa[0][2] += k0*v2; pa[0][3] += k0*v3;
        pa[1][0] += k1*v0; pa[1][1] += k1*v1; pa[1][2] += k1*v2; pa[1][3] += k1*v3;
        pa[2][0] += k2*v0; pa[2][1] += k2*v1; pa[2][2] += k2*v2; pa[2][3] += k2*v3;
        pa[3][0] += k3*v0; pa[3][1] += k3*v1; pa[3][2] += k3*v2; pa[3][3] += k3*v3;
    }
#pragma unroll
    for (int xi = 0; xi < 4; ++xi)
#pragma unroll
        for (int yi = 0; yi < 4; ++yi)
            red[w*1024 + (yg*4 + yi)*32 + xg*4 + xi] = pa[xi][yi];
    __syncthreads();
    const int e = t * 4;
    f32x4 s = *(const f32x4*)&red[e];
    s += *(const f32x4*)&red[1024 + e];
    s += *(const f32x4*)&red[2048 + e];
    s += *(const f32x4*)&red[3072 + e];
    half4 o;
#pragma unroll
    for (int i = 0; i < 4; ++i) o[i] = (_Float16)s[i];
    *(half4*)(kvT + (size_t)bid * 1024 + e) = o;
}

// ---- K3: fused softmax(q)@kvT (MFMA) + final conv (MFMA) -> relu -> out ----
__global__ __launch_bounds__(512) void k_conv_out(
    const _Float16* __restrict__ q, const _Float16* __restrict__ kvw,
    const _Float16* __restrict__ C16, const float* __restrict__ cbp,
    float* __restrict__ out) {
    __shared__ __align__(16) char sm[51200];
    __shared__ float Cb[256];
    _Float16* Ws  = (_Float16*)sm;              // [256][32]
    _Float16* kvs = (_Float16*)(sm + 16384);    // [12][1024]
    _Float16* Xt  = (_Float16*)(sm + 40960);    // [96][32]
    float*    St  = (float*)sm;                 // [128][100] epilogue overlay

    const int t = threadIdx.x;
    const int bx = blockIdx.x, b = blockIdx.y;
    const int s0 = bx * 96;
    const int n0 = bx * 8;
    const int w = t >> 6, lane = t & 63;
    const int lo = lane & 15, hi = lane >> 4;
    const int x0 = hi * 8;
    if (t < 64) *(f32x4*)&Cb[t*4] = *(const f32x4*)(cbp + t*4);

    const int o0w = (w >> 1) * 64, s0w = (w & 1) * 48;
    f32x4 acc[4][3] = {};

    // staging maps (lds-direct)
    const _Float16* csrcT = C16 + ((size_t)(w*16 + (lane>>2))) * 256 + (lane & 3) * 8;
    const _Float16* kvsrcT = kvw + (size_t)b * 98304 + w*512 + lane*8;
    _Float16* wdst = Ws + w * 512;

    // PV: waves 0..5, each owns 2 l values
    const bool pvw = (w < 6);
    const int li0 = w * 2;
    const int qrow = n0 + (lo & 7);
    const float rowmask = (lo < 8) ? 1.f : 0.f;
    const size_t hstep = (size_t)12 * ND_;
    const _Float16* qb_b = q + (size_t)b * 8 * hstep;

    half8 hq0 = {}, hq1 = {};
    if (pvw) {
        hq0 = *(const half8*)(qb_b + (size_t)li0 * ND_ + (size_t)qrow*32 + hi*8);
        hq1 = *(const half8*)(qb_b + (size_t)(li0+1) * ND_ + (size_t)qrow*32 + hi*8);
    }

    for (int kb = 0; kb < 8; ++kb) {
        // stage W slice (head kb) + kv (head kb) via lds-direct
#pragma unroll
        for (int r = 0; r < 2; ++r)
            load_lds16(csrcT + r * 32768 + kb * 32, wdst + r * 4096);
        {
            const _Float16* kvg = kvsrcT + (size_t)kb * 12288;
#pragma unroll
            for (int r = 0; r < 3; ++r)
                load_lds16(kvg + r * 4096, kvs + w*512 + r * 4096);
        }
        __syncthreads();
        // PV phase
        if (pvw) {
            half8 nq0 = hq0, nq1 = hq1;
            if (kb < 7) {
                nq0 = *(const half8*)(qb_b + (kb+1)*hstep + (size_t)li0 * ND_ + (size_t)qrow*32 + hi*8);
                nq1 = *(const half8*)(qb_b + (kb+1)*hstep + (size_t)(li0+1) * ND_ + (size_t)qrow*32 + hi*8);
            }
#pragma unroll
            for (int sub = 0; sub < 2; ++sub) {
                const half8 hq = sub ? hq1 : hq0;
                const int li = li0 + sub;
                float qv[8];
#pragma unroll
                for (int i = 0; i < 8; ++i) qv[i] = (float)hq[i];
                float m8 = fmaxf(fmaxf(fmaxf(qv[0], qv[1]), fmaxf(qv[2], qv[3])),
                                 fmaxf(fmaxf(qv[4], qv[5]), fmaxf(qv[6], qv[7])));
                m8 = fmaxf(m8, __shfl_xor(m8, 16));
                m8 = fmaxf(m8, __shfl_xor(m8, 32));
                const float mS = m8 * SCALE_;
                float ex[8]; float ssum = 0.f;
#pragma unroll
                for (int i = 0; i < 8; ++i) { ex[i] = __expf(qv[i]*SCALE_ - mS); ssum += ex[i]; }
                ssum += __shfl_xor(ssum, 16);
                ssum += __shfl_xor(ssum, 32);
                const float pin = rowmask / ssum;
                half8 af;
#pragma unroll
                for (int i = 0; i < 8; ++i) af[i] = (_Float16)(ex[i] * pin);
                const half8 b0 = *(const half8*)&kvs[li*1024 + lo*32 + hi*8];
                const half8 b1 = *(const half8*)&kvs[li*1024 + (16+lo)*32 + hi*8];
                f32x4 d0 = {}, d1 = {};
                d0 = __builtin_amdgcn_mfma_f32_16x16x32_f16(af, b0, d0, 0, 0, 0);
                d1 = __builtin_amdgcn_mfma_f32_16x16x32_f16(af, b1, d1, 0, 0, 0);
                if (hi < 2) {
#pragma unroll
                    for (int reg = 0; reg < 4; ++reg) {
                        const int srow = (hi*4 + reg)*12 + li;
                        Xt[srow*32 + lo]      = (_Float16)d0[reg];
                        Xt[srow*32 + 16 + lo] = (_Float16)d1[reg];
                    }
                }
            }
            hq0 = nq0; hq1 = nq1;
        }
        __syncthreads();
        // conv MFMA
        half8 af2[4], bf[3];
#pragma unroll
        for (int m = 0; m < 4; ++m) af2[m] = *(const half8*)&Ws[(o0w + m*16 + lo)*32 + x0];
#pragma unroll
        for (int sf = 0; sf < 3; ++sf) bf[sf] = *(const half8*)&Xt[(s0w + sf*16 + lo)*32 + x0];
#pragma unroll
        for (int m = 0; m < 4; ++m)
#pragma unroll
            for (int sf = 0; sf < 3; ++sf)
                acc[m][sf] = __builtin_amdgcn_mfma_f32_16x16x32_f16(af2[m], bf[sf], acc[m][sf], 0, 0, 0);
        __syncthreads();
    }
    // epilogue
    for (int ph = 0; ph < 2; ++ph) {
        if ((w >> 2) == ph) {
#pragma unroll
            for (int m = 0; m < 4; ++m) {
                const int ow = o0w + m*16 + hi*4;
                const int ro = ow - ph*128;
#pragma unroll
                for (int sf = 0; sf < 3; ++sf) {
                    const int s = s0w + sf*16 + lo;
#pragma unroll
                    for (int i = 0; i < 4; ++i)
                        St[(ro+i)*100 + s] = fmaxf(acc[m][sf][i] + Cb[ow+i], 0.f);
                }
            }
        }
        __syncthreads();
        {
            const int ol = t >> 2, sq = t & 3;
            const int o = ph*128 + ol;
            const int sg = s0 + sq*24;
            const int n0e = sg / 12;
            float* dst = out + ((size_t)(b*256 + o)*1024 + n0e)*12;
            const f32x4* srcv = (const f32x4*)&St[ol*100 + sq*24];
#pragma unroll
            for (int i2 = 0; i2 < 6; ++i2) *(f32x4*)(dst + i2*4) = srcv[i2];
        }
        __syncthreads();
    }
}

extern "C" void kernel_launch(void* const* d_in, const int* in_sizes, int n_in,
                              void* d_out, int out_size, void* d_ws, size_t ws_size,
                              hipStream_t stream) {
    const float* input = (const float*)d_in[0];
    const float* q_w   = (const float*)d_in[1];
    const float* q_b   = (const float*)d_in[2];
    const float* v_w   = (const float*)d_in[3];
    const float* v_b   = (const float*)d_in[4];
    const float* c_w   = (const float*)d_in[5];
    const float* c_b   = (const float*)d_in[6];
    const float* s_bank= (const float*)d_in[7];
    float* out = (float*)d_out;

    char* ws = (char*)d_ws;
    _Float16* ks16 = (_Float16*)ws;                          // 6,291,456 B
    _Float16* qh   = (_Float16*)(ws + 6291456);              // 201,326,592 B
    _Float16* vh   = qh + (size_t)100663296;                 // 201,326,592 B
    _Float16* kvT  = vh + (size_t)100663296;                 // 6,291,456 B
    _Float16* W16  = kvT + (size_t)3145728;                  // 262,144 B
    _Float16* C16  = W16 + (size_t)131072;                   // 131,072 B

    k_prep<<<dim3(64), dim3(256), 0, stream>>>(q_w, v_w, c_w, W16, C16);
    k_key_softmax<<<dim3((HLN_ + 255)/256), dim3(256), 0, stream>>>(s_bank, ks16);
    k_conv_qv<<<dim3(128, 32), dim3(512), 0, stream>>>(input, W16, q_b, v_b, qh, vh);
    k_kv<<<dim3(B_ * H_ * L_), dim3(256), 0, stream>>>(ks16, vh, kvT);
    k_conv_out<<<dim3(128, 32), dim3(512), 0, stream>>>(qh, kvT, C16, c_b, out);
}

// Round 5
// 789.089 us; speedup vs baseline: 3.0759x; 1.1244x over previous
//
#include <hip/hip_runtime.h>

#define B_   32
#define C_   256
#define N_   1024
#define L_   12
#define H_   8
#define DK_  32
#define NL_  12288
#define CNL_ 3145728
#define ND_  32768
#define HLN_ 98304
#define SCALE_ 0.17677669529663687f

typedef _Float16 half8 __attribute__((ext_vector_type(8)));
typedef _Float16 half4 __attribute__((ext_vector_type(4)));
typedef float f32x4 __attribute__((ext_vector_type(4)));

__device__ __forceinline__ int div12(int s) { return (int)(((unsigned)s * 43691u) >> 19); }

__device__ __forceinline__ void load_lds16(const _Float16* g, _Float16* l) {
    __builtin_amdgcn_global_load_lds(
        (const __attribute__((address_space(1))) void*)(const void*)g,
        (__attribute__((address_space(3))) void*)(void*)l, 16, 0, 0);
}

// ---- P: one-time fp32 -> fp16 weight conversion into FRAGMENT-ORDER layout --
// Wfrag: chunk = kb*2048 + mt*64 + o*16 + lo  holds (row m=mt*16+lo, ch kb*32+o*8..+7)
//        rows 0..255 = wq, 256..511 = wv
// Cfrag: chunk = kb*1024 + mt*64 + o*16 + lo  (m=mt*16+lo rows of cw)
__global__ __launch_bounds__(256) void k_prep(const float* __restrict__ wq,
    const float* __restrict__ wv, const float* __restrict__ cw,
    _Float16* __restrict__ Wfrag, _Float16* __restrict__ Cfrag) {
    const int gid = blockIdx.x * 256 + threadIdx.x;   // grid 96 -> 24576
    if (gid < 16384) {
        const int kb = gid >> 11, r = gid & 2047;
        const int mt = r >> 6, o = (r >> 4) & 3, lo = r & 15;
        const int m = mt * 16 + lo;
        const float* src = (m < 256 ? wq + (size_t)m * 256 : wv + (size_t)(m - 256) * 256)
                           + kb * 32 + o * 8;
        f32x4 a0 = *(const f32x4*)src, a1 = *(const f32x4*)(src + 4);
        half8 h;
#pragma unroll
        for (int i = 0; i < 4; ++i) { h[i] = (_Float16)a0[i]; h[4 + i] = (_Float16)a1[i]; }
        *(half8*)(Wfrag + (size_t)gid * 8) = h;
    } else {
        const int c = gid - 16384;                    // < 8192
        const int kb = c >> 10, r = c & 1023;
        const int mt = r >> 6, o = (r >> 4) & 3, lo = r & 15;
        const int m = mt * 16 + lo;
        const float* src = cw + (size_t)m * 256 + kb * 32 + o * 8;
        f32x4 a0 = *(const f32x4*)src, a1 = *(const f32x4*)(src + 4);
        half8 h;
#pragma unroll
        for (int i = 0; i < 4; ++i) { h[i] = (_Float16)a0[i]; h[4 + i] = (_Float16)a1[i]; }
        *(half8*)(Cfrag + (size_t)c * 8) = h;
    }
}

// ---------------- K0: softmax over DK of s_bank * scale -> ks (fp16) --------
__global__ __launch_bounds__(256) void k_key_softmax(const float* __restrict__ sb,
                                                     _Float16* __restrict__ ks) {
    int row = blockIdx.x * 256 + threadIdx.x;
    if (row >= HLN_) return;
    const f32x4* src = (const f32x4*)(sb + (size_t)row * DK_);
    float v[DK_];
#pragma unroll
    for (int i = 0; i < 8; i++) {
        f32x4 t4 = src[i];
        v[4*i+0] = t4[0]; v[4*i+1] = t4[1]; v[4*i+2] = t4[2]; v[4*i+3] = t4[3];
    }
    float m = v[0];
#pragma unroll
    for (int i = 1; i < DK_; i++) m = fmaxf(m, v[i]);
    float s = 0.f;
#pragma unroll
    for (int i = 0; i < DK_; i++) { v[i] = __expf((v[i] - m) * SCALE_); s += v[i]; }
    float inv = 1.f / s;
    half8* dst = (half8*)(ks + (size_t)row * DK_);
#pragma unroll
    for (int i = 0; i < 4; i++) {
        half8 t8;
#pragma unroll
        for (int j = 0; j < 8; j++) t8[j] = (_Float16)(v[i*8+j] * inv);
        dst[i] = t8;
    }
}

// ---------------- K1: fused q,v conv; M=512 x S=64, BK=32, frag-order LDS ----
__global__ __launch_bounds__(512, 4) void k_conv_qv(const float* __restrict__ x,
    const _Float16* __restrict__ Wfrag,
    const float* __restrict__ bqp, const float* __restrict__ bvp,
    _Float16* __restrict__ qh, _Float16* __restrict__ vh) {
    __shared__ __align__(16) char sm[73728];
    __shared__ float Bqv[512];
    _Float16* Wb = (_Float16*)sm;              // [2][16384] halfs
    _Float16* Xb = (_Float16*)(sm + 65536);    // [2][2048] halfs

    const int t = threadIdx.x;
    const int bx = blockIdx.x, b = blockIdx.y;
    const int s0 = bx * 64;
    const int w = t >> 6, lane = t & 63;
    const int lo = lane & 15, hi = lane >> 4;

    if (t < 64)       *(f32x4*)&Bqv[t*4]            = *(const f32x4*)(bqp + t*4);
    else if (t < 128) *(f32x4*)&Bqv[256 + (t-64)*4] = *(const f32x4*)(bvp + (t-64)*4);

    // X staging map: thread -> half-chunk (8B): chunk c=t>>1, j-half jh=t&1
    const int c  = t >> 1, jh = t & 1;
    const int xst = c >> 6, xoc = (c >> 4) & 3, xls = c & 15;
    const float* px = x + (size_t)b * CNL_ + (size_t)(xoc*8 + jh*4) * NL_ + s0 + xst*16 + xls;

    f32x4 acc[4][4] = {};

    // ---- prologue: stage step 0 ----
#pragma unroll
    for (int r = 0; r < 4; ++r)
        load_lds16(Wfrag + r*4096 + t*8, Wb + r*4096 + t*8);
    {
        float v0 = px[0], v1 = px[NL_], v2 = px[2*NL_], v3 = px[3*NL_];
        half4 hh; hh[0]=(_Float16)v0; hh[1]=(_Float16)v1; hh[2]=(_Float16)v2; hh[3]=(_Float16)v3;
        *(half4*)&Xb[t*4] = hh;
    }
    __syncthreads();

    for (int kb = 0; kb < 8; ++kb) {
        const int cur = kb & 1, nxt = cur ^ 1;
        if (kb < 7) {
#pragma unroll
            for (int r = 0; r < 4; ++r)
                load_lds16(Wfrag + (size_t)(kb+1)*16384 + r*4096 + t*8,
                           Wb + nxt*16384 + r*4096 + t*8);
        }
        float n0f = 0.f, n1f = 0.f, n2f = 0.f, n3f = 0.f;
        if (kb < 7) {
            const float* p = px + (size_t)(kb+1) * 32 * NL_;
            n0f = p[0]; n1f = p[NL_]; n2f = p[2*NL_]; n3f = p[3*NL_];
        }
        const _Float16* Wc = Wb + cur * 16384;
        const _Float16* Xc = Xb + cur * 2048;
        half8 af[4], bf[4];
#pragma unroll
        for (int m = 0; m < 4; ++m)
            af[m] = *(const half8*)&Wc[(((w*4 + m)*4 + hi)*16 + lo) * 8];
#pragma unroll
        for (int st = 0; st < 4; ++st)
            bf[st] = *(const half8*)&Xc[((st*4 + hi)*16 + lo) * 8];
#pragma unroll
        for (int m = 0; m < 4; ++m)
#pragma unroll
            for (int st = 0; st < 4; ++st)
                acc[m][st] = __builtin_amdgcn_mfma_f32_16x16x32_f16(af[m], bf[st], acc[m][st], 0, 0, 0);
        if (kb < 7) {
            half4 hh; hh[0]=(_Float16)n0f; hh[1]=(_Float16)n1f; hh[2]=(_Float16)n2f; hh[3]=(_Float16)n3f;
            *(half4*)&Xb[nxt*2048 + t*4] = hh;
        }
        __syncthreads();
    }

    // ---- epilogue: bias+relu+cvt, direct 8B stores (full line per wave) ----
    _Float16* dst0 = (w >> 2) ? vh : qh;
#pragma unroll
    for (int st = 0; st < 4; ++st) {
        const int sg = s0 + st*16 + lo;
        const int n = div12(sg), l = sg - n*12;
#pragma unroll
        for (int m = 0; m < 4; ++m) {
            const int o = w*64 + m*16 + hi*4;          // 0..511 (q then v)
            const f32x4 bb = *(const f32x4*)&Bqv[o];
            const int h = (w & 3)*2 + (m >> 1);
            half4 hh;
#pragma unroll
            for (int i = 0; i < 4; ++i) hh[i] = (_Float16)fmaxf(acc[m][st][i] + bb[i], 0.f);
            *(half4*)(dst0 + ((size_t)(b*8 + h)*12 + l)*ND_ + (size_t)n*32 + (m&1)*16 + hi*4) = hh;
        }
    }
}

// ---------------- K2: kvT[b,h,l][y][x] = sum_n V[n][y] * K[n][x]  (fp16 out) -
__global__ __launch_bounds__(256) void k_kv(const _Float16* __restrict__ ks,
    const _Float16* __restrict__ v, _Float16* __restrict__ kvT) {
    __shared__ float red[4096];
    const int bid = blockIdx.x;            // (b*8+h)*12 + l
    const int bh = bid / 12;
    const int l  = bid - bh * 12;
    const int h  = bh & 7;
    const int t = threadIdx.x, w = t >> 6, lane = t & 63;
    const int xg = lane & 7, yg = lane >> 3;
    const _Float16* kp = ks + ((size_t)(h*12 + l)*1024 + w*256)*32 + xg*4;
    const _Float16* vp = v  + ((size_t)(bh*12 + l)*1024 + w*256)*32 + yg*4;
    float pa[4][4] = {};
#pragma unroll 4
    for (int n = 0; n < 256; ++n) {
        half4 kk = *(const half4*)(kp + n*32);
        half4 vv = *(const half4*)(vp + n*32);
        float k0=(float)kk[0], k1=(float)kk[1], k2=(float)kk[2], k3=(float)kk[3];
        float v0=(float)vv[0], v1=(float)vv[1], v2=(float)vv[2], v3=(float)vv[3];
        pa[0][0] += k0*v0; pa[0][1] += k0*v1; pa[0][2] += k0*v2; pa[0][3] += k0*v3;
        pa[1][0] += k1*v0; pa[1][1] += k1*v1; pa[1][2] += k1*v2; pa[1][3] += k1*v3;
        pa[2][0] += k2*v0; pa[2][1] += k2*v1; pa[2][2] += k2*v2; pa[2][3] += k2*v3;
        pa[3][0] += k3*v0; pa[3][1] += k3*v1; pa[3][2] += k3*v2; pa[3][3] += k3*v3;
    }
#pragma unroll
    for (int xi = 0; xi < 4; ++xi)
#pragma unroll
        for (int yi = 0; yi < 4; ++yi)
            red[w*1024 + (yg*4 + yi)*32 + xg*4 + xi] = pa[xi][yi];
    __syncthreads();
    const int e = t * 4;
    f32x4 s = *(const f32x4*)&red[e];
    s += *(const f32x4*)&red[1024 + e];
    s += *(const f32x4*)&red[2048 + e];
    s += *(const f32x4*)&red[3072 + e];
    half4 o;
#pragma unroll
    for (int i = 0; i < 4; ++i) o[i] = (_Float16)s[i];
    *(half4*)(kvT + (size_t)bid * 1024 + e) = o;
}

// ---- K3: fused softmax(q)@kvT (MFMA) + final conv (MFMA) -> relu -> out ----
__global__ __launch_bounds__(512, 4) void k_conv_out(
    const _Float16* __restrict__ q, const _Float16* __restrict__ kvw,
    const _Float16* __restrict__ Cfrag, const float* __restrict__ cbp,
    float* __restrict__ out) {
    __shared__ __align__(16) char sm[63488];
    __shared__ float Cb[256];
    _Float16* Wc  = (_Float16*)sm;               // [2][8192] halfs
    _Float16* kvs = (_Float16*)(sm + 32768);     // [12][1024] halfs
    _Float16* Xt  = (_Float16*)(sm + 57344);     // [3072] halfs (frag order)

    const int t = threadIdx.x;
    const int bx = blockIdx.x, b = blockIdx.y;
    const int s0 = bx * 96;
    const int n0 = bx * 8;
    const int w = t >> 6, lane = t & 63;
    const int lo = lane & 15, hi = lane >> 4;
    if (t < 64) *(f32x4*)&Cb[t*4] = *(const f32x4*)(cbp + t*4);

    f32x4 acc[4][3] = {};
    const _Float16* kvsrc = kvw + (size_t)b * 98304 + t*8;

    // PV: waves 0..5, each owns 2 l values
    const bool pvw = (w < 6);
    const int li0 = w * 2;
    const int qrow = n0 + (lo & 7);
    const float rowmask = (lo < 8) ? 1.f : 0.f;
    const size_t hstep = (size_t)12 * ND_;
    const _Float16* qb_b = q + (size_t)b * 8 * hstep;

    half8 hq0 = {}, hq1 = {};
    if (pvw) {
        hq0 = *(const half8*)(qb_b + (size_t)li0 * ND_ + (size_t)qrow*32 + hi*8);
        hq1 = *(const half8*)(qb_b + (size_t)(li0+1) * ND_ + (size_t)qrow*32 + hi*8);
    }

    // prologue: stage W(0), kv(0)
#pragma unroll
    for (int r = 0; r < 2; ++r)
        load_lds16(Cfrag + r*4096 + t*8, Wc + r*4096 + t*8);
#pragma unroll
    for (int r = 0; r < 3; ++r)
        load_lds16(kvsrc + r*4096, kvs + r*4096 + t*8);
    __syncthreads();

    for (int kb = 0; kb < 8; ++kb) {
        const int cur = kb & 1, nxt = cur ^ 1;
        if (kb < 7) {
#pragma unroll
            for (int r = 0; r < 2; ++r)
                load_lds16(Cfrag + (size_t)(kb+1)*8192 + r*4096 + t*8,
                           Wc + nxt*8192 + r*4096 + t*8);
        }
        // ---- PV phase ----
        if (pvw) {
            half8 nq0 = hq0, nq1 = hq1;
            if (kb < 7) {
                nq0 = *(const half8*)(qb_b + (kb+1)*hstep + (size_t)li0 * ND_ + (size_t)qrow*32 + hi*8);
                nq1 = *(const half8*)(qb_b + (kb+1)*hstep + (size_t)(li0+1) * ND_ + (size_t)qrow*32 + hi*8);
            }
#pragma unroll
            for (int sub = 0; sub < 2; ++sub) {
                const half8 hq = sub ? hq1 : hq0;
                const int li = li0 + sub;
                float qv[8];
#pragma unroll
                for (int i = 0; i < 8; ++i) qv[i] = (float)hq[i];
                float m8 = fmaxf(fmaxf(fmaxf(qv[0], qv[1]), fmaxf(qv[2], qv[3])),
                                 fmaxf(fmaxf(qv[4], qv[5]), fmaxf(qv[6], qv[7])));
                m8 = fmaxf(m8, __shfl_xor(m8, 16));
                m8 = fmaxf(m8, __shfl_xor(m8, 32));
                const float mS = m8 * SCALE_;
                float ex[8]; float ssum = 0.f;
#pragma unroll
                for (int i = 0; i < 8; ++i) { ex[i] = __expf(qv[i]*SCALE_ - mS); ssum += ex[i]; }
                ssum += __shfl_xor(ssum, 16);
                ssum += __shfl_xor(ssum, 32);
                const float pin = rowmask / ssum;
                half8 af;
#pragma unroll
                for (int i = 0; i < 8; ++i) af[i] = (_Float16)(ex[i] * pin);
                const half8 b0 = *(const half8*)&kvs[li*1024 + lo*32 + hi*8];
                const half8 b1 = *(const half8*)&kvs[li*1024 + (16+lo)*32 + hi*8];
                f32x4 d0 = {}, d1 = {};
                d0 = __builtin_amdgcn_mfma_f32_16x16x32_f16(af, b0, d0, 0, 0, 0);
                d1 = __builtin_amdgcn_mfma_f32_16x16x32_f16(af, b1, d1, 0, 0, 0);
                if (hi < 2) {
#pragma unroll
                    for (int reg = 0; reg < 4; ++reg) {
                        const int s = (hi*4 + reg)*12 + li;
                        const int cb_ = (s >> 4)*64 + (s & 15);
                        Xt[(cb_ + (lo >> 3)*16)*8 + (lo & 7)]       = (_Float16)d0[reg];
                        Xt[(cb_ + (2 + (lo >> 3))*16)*8 + (lo & 7)] = (_Float16)d1[reg];
                    }
                }
            }
            hq0 = nq0; hq1 = nq1;
        }
        __syncthreads();
        // ---- conv MFMA ----
        const _Float16* Wcc = Wc + cur * 8192;
        half8 af2[4], bf[3];
#pragma unroll
        for (int m = 0; m < 4; ++m)
            af2[m] = *(const half8*)&Wcc[((((w>>1)*4 + m)*4 + hi)*16 + lo) * 8];
#pragma unroll
        for (int sf = 0; sf < 3; ++sf)
            bf[sf] = *(const half8*)&Xt[((((w&1)*3 + sf)*4 + hi)*16 + lo) * 8];
#pragma unroll
        for (int m = 0; m < 4; ++m)
#pragma unroll
            for (int sf = 0; sf < 3; ++sf)
                acc[m][sf] = __builtin_amdgcn_mfma_f32_16x16x32_f16(af2[m], bf[sf], acc[m][sf], 0, 0, 0);
        if (kb < 7) {
#pragma unroll
            for (int r = 0; r < 3; ++r)
                load_lds16(kvsrc + (size_t)(kb+1)*12288 + r*4096, kvs + r*4096 + t*8);
        }
        __syncthreads();
    }

    // ---- epilogue: bias + relu, direct coalesced f32 stores ----
#pragma unroll
    for (int m = 0; m < 4; ++m) {
        const int o = (w>>1)*64 + m*16 + hi*4;
        const f32x4 bb = *(const f32x4*)&Cb[o];
#pragma unroll
        for (int sf = 0; sf < 3; ++sf) {
            const int s = s0 + (w&1)*48 + sf*16 + lo;
            float* dst = out + (size_t)(b*256 + o)*12288 + s;
#pragma unroll
            for (int i = 0; i < 4; ++i)
                dst[(size_t)i * 12288] = fmaxf(acc[m][sf][i] + bb[i], 0.f);
        }
    }
}

extern "C" void kernel_launch(void* const* d_in, const int* in_sizes, int n_in,
                              void* d_out, int out_size, void* d_ws, size_t ws_size,
                              hipStream_t stream) {
    const float* input = (const float*)d_in[0];
    const float* q_w   = (const float*)d_in[1];
    const float* q_b   = (const float*)d_in[2];
    const float* v_w   = (const float*)d_in[3];
    const float* v_b   = (const float*)d_in[4];
    const float* c_w   = (const float*)d_in[5];
    const float* c_b   = (const float*)d_in[6];
    const float* s_bank= (const float*)d_in[7];
    float* out = (float*)d_out;

    char* ws = (char*)d_ws;
    _Float16* ks16 = (_Float16*)ws;                          // 6,291,456 B
    _Float16* qh   = (_Float16*)(ws + 6291456);              // 201,326,592 B
    _Float16* vh   = qh + (size_t)100663296;                 // 201,326,592 B
    _Float16* kvT  = vh + (size_t)100663296;                 // 6,291,456 B
    _Float16* Wfrag= kvT + (size_t)3145728;                  // 262,144 B
    _Float16* Cfrag= Wfrag + (size_t)131072;                 // 131,072 B

    k_prep<<<dim3(96), dim3(256), 0, stream>>>(q_w, v_w, c_w, Wfrag, Cfrag);
    k_key_softmax<<<dim3((HLN_ + 255)/256), dim3(256), 0, stream>>>(s_bank, ks16);
    k_conv_qv<<<dim3(192, 32), dim3(512), 0, stream>>>(input, Wfrag, q_b, v_b, qh, vh);
    k_kv<<<dim3(B_ * H_ * L_), dim3(256), 0, stream>>>(ks16, vh, kvT);
    k_conv_out<<<dim3(128, 32), dim3(512), 0, stream>>>(qh, kvT, Cfrag, c_b, out);
}